// Round 1
// baseline (265.606 us; speedup 1.0000x reference)
//
#include <hip/hip_runtime.h>
#include <math.h>

#define BB 4
#define LQ 8400
#define NH 8
#define LVTOT 8500
#define HD 32

typedef __attribute__((ext_vector_type(8))) short short8;
typedef __attribute__((ext_vector_type(4))) float f32x4;
typedef unsigned short ushort_t;

__device__ __forceinline__ ushort_t f2bf(float f) {
    union { float f; unsigned u; } v; v.f = f;
    unsigned r = v.u + 0x7fffu + ((v.u >> 16) & 1u);   // RNE
    return (ushort_t)(r >> 16);
}
__device__ __forceinline__ float bflo(unsigned u) {
    union { unsigned u; float f; } x; x.u = u << 16; return x.f;
}
__device__ __forceinline__ float bfhi(unsigned u) {
    union { unsigned u; float f; } x; x.u = u & 0xffff0000u; return x.f;
}

// async global->LDS DMA, 16 B per lane (wave-uniform LDS base + lane*16)
__device__ __forceinline__ void dma16(const ushort_t* g, ushort_t* l) {
    __builtin_amdgcn_global_load_lds(
        (const __attribute__((address_space(1))) void*)g,
        (__attribute__((address_space(3))) void*)l, 16, 0, 0);
}

// ---------------------------------------------------------------------------
// Merged prep: blocks [0,8500) cast value, [8500,16900) cast query,
// [16900,17796) build BT (transposed bf16 weights, 896 rows x 256 k:
// rows 0..255 = Wv^T, 256..639 = [Woff|Wattn]^T, 640..895 = Wo^T).
// ---------------------------------------------------------------------------
__global__ __launch_bounds__(256) void prep_all(
    const float* __restrict__ value, const float* __restrict__ query,
    const float* __restrict__ Wv, const float* __restrict__ Woff,
    const float* __restrict__ Wattn, const float* __restrict__ Wo,
    ushort_t* __restrict__ value_b, ushort_t* __restrict__ query_b,
    ushort_t* __restrict__ BT)
{
    const int bid = blockIdx.x;
    if (bid < 16900) {
        const float* src = (bid < 8500) ? value : query;
        ushort_t* dst = (bid < 8500) ? value_b : query_b;
        int i = (bid < 8500 ? bid : bid - 8500) * 256 + threadIdx.x;
        float4 f = ((const float4*)src)[i];
        ushort4 o;
        o.x = f2bf(f.x); o.y = f2bf(f.y); o.z = f2bf(f.z); o.w = f2bf(f.w);
        ((ushort4*)dst)[i] = o;
    } else {
        int idx = (bid - 16900) * 256 + threadIdx.x;   // 896*256
        int r = idx >> 8, k = idx & 255;
        float v;
        if (r < 256) v = Wv[k * 256 + r];
        else if (r < 640) {
            int n = r - 256;
            v = (n < 256) ? Woff[k * 256 + n] : Wattn[k * 128 + (n - 256)];
        } else v = Wo[k * 256 + (r - 640)];
        BT[idx] = f2bf(v);
    }
}

// ---------------------------------------------------------------------------
// Shared GEMM core: 128x128 tile, 4 waves, BK=64. Staging via global_load_lds
// dwordx4; XOR swizzle on the GLOBAL segment so linear DMA placement yields
// physical seg = logical ^ (row&7).
// ---------------------------------------------------------------------------
__device__ __forceinline__ void gemm_core(
    const ushort_t* __restrict__ A, const ushort_t* __restrict__ B, int M,
    int m0, int n0, ushort_t* Asl, ushort_t* Bsl, f32x4 acc[4][4])
{
    const int tid  = threadIdx.x;
    const int wave = tid >> 6, lane = tid & 63;
    const int quad = lane >> 4, mr = lane & 15;
    const int wm   = (wave >> 1) * 64, wn = (wave & 1) * 64;
    const int oct  = lane >> 3;       // 0..7 row-in-wave-slab
    const int bseg = lane & 7;        // physical 16B slot within row

    for (int k0 = 0; k0 < 256; k0 += 64) {
        __syncthreads();              // prior iteration's reads done
        #pragma unroll
        for (int i = 0; i < 4; i++) {
            int m  = i * 32 + wave * 8 + oct;          // block-relative row
            int gs = bseg ^ (m & 7);                   // swizzled source seg
            int am = min(m0 + m, M - 1);
            dma16(A + (size_t)am * 256 + k0 + gs * 8,
                  Asl + (size_t)(i * 32 + wave * 8) * 64 + lane * 8);
            int bn = n0 + m;
            dma16(B + (size_t)bn * 256 + k0 + gs * 8,
                  Bsl + (size_t)(i * 32 + wave * 8) * 64 + lane * 8);
        }
        __syncthreads();              // DMA landed
        #pragma unroll
        for (int ks = 0; ks < 2; ks++) {
            short8 af[4], bf[4];
            const int ksl = ks * 4 + quad;
            #pragma unroll
            for (int i = 0; i < 4; i++) {
                int m = wm + i * 16 + mr;
                af[i] = *(const short8*)&Asl[m * 64 + (ksl ^ (m & 7)) * 8];
                int n = wn + i * 16 + mr;
                bf[i] = *(const short8*)&Bsl[n * 64 + (ksl ^ (n & 7)) * 8];
            }
            #pragma unroll
            for (int i = 0; i < 4; i++)
                #pragma unroll
                for (int j = 0; j < 4; j++)
                    acc[i][j] = __builtin_amdgcn_mfma_f32_16x16x32_bf16(
                        af[i], bf[j], acc[i][j], 0, 0, 0);
        }
    }
}

// ---------------------------------------------------------------------------
// GEMM1: value_b @ Wv^T -> vperm (fp32, head-permuted layout)
// ---------------------------------------------------------------------------
__global__ __launch_bounds__(256, 3) void gemm_v(
    const ushort_t* __restrict__ Av, const ushort_t* __restrict__ BT,
    const float* __restrict__ bv, float* __restrict__ vperm)
{
    __shared__ ushort_t Asl[128 * 64];
    __shared__ ushort_t Bsl[128 * 64];

    const int m0 = (blockIdx.x % 266) * 128;
    const int n0 = (blockIdx.x / 266) * 128;
    const int M = 34000;

    f32x4 acc[4][4];
    #pragma unroll
    for (int i = 0; i < 4; i++)
        #pragma unroll
        for (int j = 0; j < 4; j++) acc[i][j] = (f32x4){0.f, 0.f, 0.f, 0.f};

    gemm_core(Av, BT, M, m0, n0, Asl, Bsl, acc);

    const int tid  = threadIdx.x;
    const int wave = tid >> 6, lane = tid & 63;
    const int quad = lane >> 4, mr = lane & 15;
    const int wm   = (wave >> 1) * 64, wn = (wave & 1) * 64;

    #pragma unroll
    for (int i = 0; i < 4; i++) {
        const int rbase = m0 + wm + i * 16 + quad * 4;
        #pragma unroll
        for (int j = 0; j < 4; j++) {
            const int c = n0 + wn + j * 16 + mr;
            #pragma unroll
            for (int reg = 0; reg < 4; reg++) {
                int row = rbase + reg;
                if (row >= M) continue;
                float o = acc[i][j][reg] + bv[c];
                int b = row / LVTOT, pix = row - b * LVTOT;
                int h = c >> 5, d = c & 31;
                vperm[(((size_t)(b * NH + h)) * LVTOT + pix) * HD + d] = o;
            }
        }
    }
}

// ---------------------------------------------------------------------------
// GEMM2: query_b @ [Woff|Wattn]^T -> off_b (bf16), awl_b (bf16)
// ---------------------------------------------------------------------------
__global__ __launch_bounds__(256, 3) void gemm_q(
    const ushort_t* __restrict__ Aq, const ushort_t* __restrict__ BTq,
    const float* __restrict__ boff, const float* __restrict__ battn,
    ushort_t* __restrict__ off_b, ushort_t* __restrict__ awl_b)
{
    __shared__ ushort_t Asl[128 * 64];
    __shared__ ushort_t Bsl[128 * 64];

    const int m0 = (blockIdx.x % 263) * 128;
    const int n0 = (blockIdx.x / 263) * 128;
    const int M = 33600;

    f32x4 acc[4][4];
    #pragma unroll
    for (int i = 0; i < 4; i++)
        #pragma unroll
        for (int j = 0; j < 4; j++) acc[i][j] = (f32x4){0.f, 0.f, 0.f, 0.f};

    gemm_core(Aq, BTq, M, m0, n0, Asl, Bsl, acc);

    const int tid  = threadIdx.x;
    const int wave = tid >> 6, lane = tid & 63;
    const int quad = lane >> 4, mr = lane & 15;
    const int wm   = (wave >> 1) * 64, wn = (wave & 1) * 64;

    #pragma unroll
    for (int i = 0; i < 4; i++) {
        const int rbase = m0 + wm + i * 16 + quad * 4;
        #pragma unroll
        for (int j = 0; j < 4; j++) {
            const int c = n0 + wn + j * 16 + mr;
            #pragma unroll
            for (int reg = 0; reg < 4; reg++) {
                int row = rbase + reg;
                if (row >= M) continue;
                float val = acc[i][j][reg];
                if (c < 256) off_b[(size_t)row * 256 + c] = f2bf(val + boff[c]);
                else awl_b[(size_t)row * 128 + (c - 256)] = f2bf(val + battn[c - 256]);
            }
        }
    }
}

// ---------------------------------------------------------------------------
// GEMM3: sampled(bf16) @ Wo + bo -> out fp32
// ---------------------------------------------------------------------------
__global__ __launch_bounds__(256, 3) void gemm_out(
    const ushort_t* __restrict__ A, const ushort_t* __restrict__ BT,
    const float* __restrict__ bo, float* __restrict__ out)
{
    __shared__ ushort_t Asl[128 * 64];
    __shared__ ushort_t Bsl[128 * 64];

    const int m0 = (blockIdx.x % 263) * 128;
    const int n0 = (blockIdx.x / 263) * 128;
    const int M = 33600;

    f32x4 acc[4][4];
    #pragma unroll
    for (int i = 0; i < 4; i++)
        #pragma unroll
        for (int j = 0; j < 4; j++) acc[i][j] = (f32x4){0.f, 0.f, 0.f, 0.f};

    gemm_core(A, BT, M, m0, n0, Asl, Bsl, acc);

    const int tid  = threadIdx.x;
    const int wave = tid >> 6, lane = tid & 63;
    const int quad = lane >> 4, mr = lane & 15;
    const int wm   = (wave >> 1) * 64, wn = (wave & 1) * 64;

    #pragma unroll
    for (int i = 0; i < 4; i++) {
        const int rbase = m0 + wm + i * 16 + quad * 4;
        #pragma unroll
        for (int j = 0; j < 4; j++) {
            const int c = n0 + wn + j * 16 + mr;
            #pragma unroll
            for (int reg = 0; reg < 4; reg++) {
                int row = rbase + reg;
                if (row >= M) continue;
                out[(size_t)row * 256 + c] = acc[i][j][reg] + bo[c];
            }
        }
    }
}

// ---------------------------------------------------------------------------
// Sampler v6: fp32 vperm gathers (float4/corner), 32-bit saddr-form offsets,
// fast-rcp softmax. Block = 4 queries; wave = query; 8 lanes per head, 4
// dims per lane.
// ---------------------------------------------------------------------------
__global__ __launch_bounds__(256) void msda_sample(
    const float* __restrict__ vperm, const ushort_t* __restrict__ off,
    const ushort_t* __restrict__ awl, const float* __restrict__ refp,
    ushort_t* __restrict__ sampled)
{
    __shared__ float  s_ref[32];
    __shared__ float4 s_wv[544];   // (q*8+h)*17 + (l*4+p), q<4
    __shared__ int4   s_iv[544];   // byte offsets within (b,h) plane

    const int tid = threadIdx.x;
    const int bq0 = blockIdx.x * 4;

    if (tid < 32) s_ref[tid] = refp[(size_t)bq0 * 8 + tid];
    __syncthreads();

    const int Hs[4]   = {80, 40, 20, 10};
    const int base[4] = {0, 6400, 8000, 8400};

    #pragma unroll
    for (int it = 0; it < 2; it++) {
        const int s = it * 256 + tid;
        const int q = s >> 7, r = s & 127;
        const int h = r >> 4, l = (r >> 2) & 3, p = r & 3;
        const int bq = bq0 + q;
        const int Wl = Hs[l], Hl = Hs[l];
        unsigned od = *(const unsigned*)(off + (size_t)bq * 256 + h * 32 + l * 8 + p * 2);
        float ox = bflo(od), oy = bfhi(od);
        float lgt = bflo((unsigned)awl[(size_t)bq * 128 + h * 16 + l * 4 + p]);
        // softmax over the 16-lane (q,h) group, no max pass (bounded logits)
        float e = __expf(lgt);
        float sum = e;
        sum += __shfl_xor(sum, 1, 16);
        sum += __shfl_xor(sum, 2, 16);
        sum += __shfl_xor(sum, 4, 16);
        sum += __shfl_xor(sum, 8, 16);
        float aw = e * __builtin_amdgcn_rcpf(sum);

        float rx = s_ref[q * 8 + l * 2 + 0];
        float ry = s_ref[q * 8 + l * 2 + 1];
        float x = rx * (float)Wl + ox - 0.5f;
        float y = ry * (float)Hl + oy - 0.5f;
        float x0f = floorf(x), y0f = floorf(y);
        float wx = x - x0f, wy = y - y0f;
        int x0 = (int)x0f, y0 = (int)y0f;
        bool vx0 = (x0 >= 0) & (x0 < Wl);
        bool vx1 = (x0 + 1 >= 0) & (x0 + 1 < Wl);
        bool vy0 = (y0 >= 0) & (y0 < Hl);
        bool vy1 = (y0 + 1 >= 0) & (y0 + 1 < Hl);
        int cx0 = min(max(x0, 0), Wl - 1);
        int cx1 = min(max(x0 + 1, 0), Wl - 1);
        int cy0 = min(max(y0, 0), Hl - 1);
        int cy1 = min(max(y0 + 1, 0), Hl - 1);
        float w00 = (vx0 && vy0) ? (1.f - wx) * (1.f - wy) * aw : 0.f;
        float w01 = (vx1 && vy0) ? wx * (1.f - wy) * aw : 0.f;
        float w10 = (vx0 && vy1) ? (1.f - wx) * wy * aw : 0.f;
        float w11 = (vx1 && vy1) ? wx * wy * aw : 0.f;
        const int rec = (q * 8 + h) * 17 + (l * 4 + p);
        s_wv[rec] = make_float4(w00, w01, w10, w11);
        s_iv[rec] = make_int4((base[l] + cy0 * Wl + cx0) << 7,
                              (base[l] + cy0 * Wl + cx1) << 7,
                              (base[l] + cy1 * Wl + cx0) << 7,
                              (base[l] + cy1 * Wl + cx1) << 7);
    }
    __syncthreads();

    const int q    = tid >> 6;          // wave = query
    const int lane = tid & 63;
    const int h    = lane >> 3;
    const int d4   = (lane & 7) * 4;    // 4 dims per lane
    const int bq   = bq0 + q;
    const int b    = bq / LQ;
    const unsigned lane_off = (unsigned)(b * NH + h) * (unsigned)(LVTOT * HD * 4)
                            + (unsigned)(d4 * 4);
    const char* vpc = (const char*)vperm;

    f32x4 acc = (f32x4){0.f, 0.f, 0.f, 0.f};
    #pragma unroll
    for (int pt = 0; pt < 16; pt++) {
        const int rec = (q * 8 + h) * 17 + pt;
        float4 w  = s_wv[rec];
        int4   iv = s_iv[rec];
        f32x4 v0 = *(const f32x4*)(vpc + (lane_off + (unsigned)iv.x));
        f32x4 v1 = *(const f32x4*)(vpc + (lane_off + (unsigned)iv.y));
        f32x4 v2 = *(const f32x4*)(vpc + (lane_off + (unsigned)iv.z));
        f32x4 v3 = *(const f32x4*)(vpc + (lane_off + (unsigned)iv.w));
        acc = __builtin_elementwise_fma((f32x4){w.x, w.x, w.x, w.x}, v0, acc);
        acc = __builtin_elementwise_fma((f32x4){w.y, w.y, w.y, w.y}, v1, acc);
        acc = __builtin_elementwise_fma((f32x4){w.z, w.z, w.z, w.z}, v2, acc);
        acc = __builtin_elementwise_fma((f32x4){w.w, w.w, w.w, w.w}, v3, acc);
    }
    ushort4 o;
    o.x = f2bf(acc[0]); o.y = f2bf(acc[1]);
    o.z = f2bf(acc[2]); o.w = f2bf(acc[3]);
    *(ushort4*)(sampled + (size_t)bq * 256 + h * 32 + d4) = o;
}

extern "C" void kernel_launch(void* const* d_in, const int* in_sizes, int n_in,
                              void* d_out, int out_size, void* d_ws, size_t ws_size,
                              hipStream_t stream) {
    const float* query = (const float*)d_in[0];
    const float* refp  = (const float*)d_in[1];
    const float* value = (const float*)d_in[2];
    const float* Wv    = (const float*)d_in[4];
    const float* bv    = (const float*)d_in[5];
    const float* Woff  = (const float*)d_in[6];
    const float* boff  = (const float*)d_in[7];
    const float* Wattn = (const float*)d_in[8];
    const float* battn = (const float*)d_in[9];
    const float* Wo    = (const float*)d_in[10];
    const float* bo    = (const float*)d_in[11];
    float* out = (float*)d_out;

    // Workspace layout (78.5 MB total), with sequential-alias reuse:
    //  R1: 8,704,000 sh  value_b (prep->gemm_v)   then off_b (gemm_q->sampler)
    //  R2: 8,601,600 sh  query_b (prep->gemm_q)   then sampled (sampler->gemm_out)
    //  R3: 4,300,800 sh  awl_b
    //  R4: 8,704,000 f32 vperm (fp32)
    //  R5:   229,376 sh  BT
    ushort_t* ws = (ushort_t*)d_ws;
    ushort_t* R1 = ws;
    ushort_t* R2 = R1 + 8704000;
    ushort_t* R3 = R2 + 8601600;
    float*  vperm = (float*)(R3 + 4300800);
    ushort_t* BT = (ushort_t*)(vperm + 8704000);

    prep_all<<<dim3(17796), 256, 0, stream>>>(
        value, query, Wv, Woff, Wattn, Wo, R1, R2, BT);

    gemm_v<<<dim3(532), 256, 0, stream>>>(R1, BT, bv, vperm);

    gemm_q<<<dim3(789), 256, 0, stream>>>(R2, BT + 65536, boff, battn, R1, R3);

    msda_sample<<<dim3(8400), 256, 0, stream>>>(vperm, R1, R3, refp, R2);

    gemm_out<<<dim3(526), 256, 0, stream>>>(R2, BT + 163840, bo, out);
}

// Round 2
// 248.283 us; speedup vs baseline: 1.0698x; 1.0698x over previous
//
#include <hip/hip_runtime.h>
#include <math.h>

#define BB 4
#define LQ 8400
#define NH 8
#define LVTOT 8500
#define HD 32

typedef __attribute__((ext_vector_type(8))) short short8;
typedef __attribute__((ext_vector_type(4))) float f32x4;
typedef __attribute__((ext_vector_type(2))) float f32x2;
typedef unsigned short ushort_t;

__device__ __forceinline__ ushort_t f2bf(float f) {
    union { float f; unsigned u; } v; v.f = f;
    unsigned r = v.u + 0x7fffu + ((v.u >> 16) & 1u);   // RNE
    return (ushort_t)(r >> 16);
}
__device__ __forceinline__ float bflo(unsigned u) {
    union { unsigned u; float f; } x; x.u = u << 16; return x.f;
}
__device__ __forceinline__ float bfhi(unsigned u) {
    union { unsigned u; float f; } x; x.u = u & 0xffff0000u; return x.f;
}
__device__ __forceinline__ f32x2 up2(unsigned u) {
    return (f32x2){bflo(u), bfhi(u)};
}

// async global->LDS DMA, 16 B per lane (wave-uniform LDS base + lane*16)
__device__ __forceinline__ void dma16(const ushort_t* g, ushort_t* l) {
    __builtin_amdgcn_global_load_lds(
        (const __attribute__((address_space(1))) void*)g,
        (__attribute__((address_space(3))) void*)l, 16, 0, 0);
}

// ---------------------------------------------------------------------------
// Merged prep: blocks [0,8500) cast value, [8500,16900) cast query,
// [16900,17796) build BT (transposed bf16 weights, 896 rows x 256 k:
// rows 0..255 = Wv^T, 256..639 = [Woff|Wattn]^T, 640..895 = Wo^T).
// ---------------------------------------------------------------------------
__global__ __launch_bounds__(256) void prep_all(
    const float* __restrict__ value, const float* __restrict__ query,
    const float* __restrict__ Wv, const float* __restrict__ Woff,
    const float* __restrict__ Wattn, const float* __restrict__ Wo,
    ushort_t* __restrict__ value_b, ushort_t* __restrict__ query_b,
    ushort_t* __restrict__ BT)
{
    const int bid = blockIdx.x;
    if (bid < 16900) {
        const float* src = (bid < 8500) ? value : query;
        ushort_t* dst = (bid < 8500) ? value_b : query_b;
        int i = (bid < 8500 ? bid : bid - 8500) * 256 + threadIdx.x;
        float4 f = ((const float4*)src)[i];
        ushort4 o;
        o.x = f2bf(f.x); o.y = f2bf(f.y); o.z = f2bf(f.z); o.w = f2bf(f.w);
        ((ushort4*)dst)[i] = o;
    } else {
        int idx = (bid - 16900) * 256 + threadIdx.x;   // 896*256
        int r = idx >> 8, k = idx & 255;
        float v;
        if (r < 256) v = Wv[k * 256 + r];
        else if (r < 640) {
            int n = r - 256;
            v = (n < 256) ? Woff[k * 256 + n] : Wattn[k * 128 + (n - 256)];
        } else v = Wo[k * 256 + (r - 640)];
        BT[idx] = f2bf(v);
    }
}

// ---------------------------------------------------------------------------
// Shared GEMM core: 128x128 tile, 4 waves, BK=64. Staging via global_load_lds
// dwordx4; XOR swizzle on the GLOBAL segment so linear DMA placement yields
// physical seg = logical ^ (row&7).
// ---------------------------------------------------------------------------
__device__ __forceinline__ void gemm_core(
    const ushort_t* __restrict__ A, const ushort_t* __restrict__ B, int M,
    int m0, int n0, ushort_t* Asl, ushort_t* Bsl, f32x4 acc[4][4])
{
    const int tid  = threadIdx.x;
    const int wave = tid >> 6, lane = tid & 63;
    const int quad = lane >> 4, mr = lane & 15;
    const int wm   = (wave >> 1) * 64, wn = (wave & 1) * 64;
    const int oct  = lane >> 3;       // 0..7 row-in-wave-slab
    const int bseg = lane & 7;        // physical 16B slot within row

    for (int k0 = 0; k0 < 256; k0 += 64) {
        __syncthreads();              // prior iteration's reads done
        #pragma unroll
        for (int i = 0; i < 4; i++) {
            int m  = i * 32 + wave * 8 + oct;          // block-relative row
            int gs = bseg ^ (m & 7);                   // swizzled source seg
            int am = min(m0 + m, M - 1);
            dma16(A + (size_t)am * 256 + k0 + gs * 8,
                  Asl + (size_t)(i * 32 + wave * 8) * 64 + lane * 8);
            int bn = n0 + m;
            dma16(B + (size_t)bn * 256 + k0 + gs * 8,
                  Bsl + (size_t)(i * 32 + wave * 8) * 64 + lane * 8);
        }
        __syncthreads();              // DMA landed
        #pragma unroll
        for (int ks = 0; ks < 2; ks++) {
            short8 af[4], bf[4];
            const int ksl = ks * 4 + quad;
            #pragma unroll
            for (int i = 0; i < 4; i++) {
                int m = wm + i * 16 + mr;
                af[i] = *(const short8*)&Asl[m * 64 + (ksl ^ (m & 7)) * 8];
                int n = wn + i * 16 + mr;
                bf[i] = *(const short8*)&Bsl[n * 64 + (ksl ^ (n & 7)) * 8];
            }
            #pragma unroll
            for (int i = 0; i < 4; i++)
                #pragma unroll
                for (int j = 0; j < 4; j++)
                    acc[i][j] = __builtin_amdgcn_mfma_f32_16x16x32_bf16(
                        af[i], bf[j], acc[i][j], 0, 0, 0);
        }
    }
}

// ---------------------------------------------------------------------------
// Fused GEMM1 (value->vperm bf16, 532 blocks) + GEMM2 (query->off/awl, 789)
// ---------------------------------------------------------------------------
__global__ __launch_bounds__(256, 3) void gemm_fused(
    const ushort_t* __restrict__ Av, const ushort_t* __restrict__ Aq,
    const ushort_t* __restrict__ BT,
    const float* __restrict__ bv, const float* __restrict__ boff,
    const float* __restrict__ battn,
    ushort_t* __restrict__ vperm, ushort_t* __restrict__ off_b,
    ushort_t* __restrict__ awl_b)
{
    __shared__ ushort_t Asl[128 * 64];
    __shared__ ushort_t Bsl[128 * 64];

    const int bid = blockIdx.x;
    int mode, m0, n0, M;
    const ushort_t *A, *B;
    if (bid < 532) { mode = 0; m0 = (bid % 266) * 128; n0 = (bid / 266) * 128;
                     A = Av; B = BT; M = 34000; }
    else { int b2 = bid - 532;
           mode = 1; m0 = (b2 % 263) * 128; n0 = (b2 / 263) * 128;
           A = Aq; B = BT + 65536; M = 33600; }

    f32x4 acc[4][4];
    #pragma unroll
    for (int i = 0; i < 4; i++)
        #pragma unroll
        for (int j = 0; j < 4; j++) acc[i][j] = (f32x4){0.f, 0.f, 0.f, 0.f};

    gemm_core(A, B, M, m0, n0, Asl, Bsl, acc);

    const int tid  = threadIdx.x;
    const int wave = tid >> 6, lane = tid & 63;
    const int quad = lane >> 4, mr = lane & 15;
    const int wm   = (wave >> 1) * 64, wn = (wave & 1) * 64;

    #pragma unroll
    for (int i = 0; i < 4; i++) {
        const int rbase = m0 + wm + i * 16 + quad * 4;
        #pragma unroll
        for (int j = 0; j < 4; j++) {
            const int c = n0 + wn + j * 16 + mr;
            #pragma unroll
            for (int reg = 0; reg < 4; reg++) {
                int row = rbase + reg;
                if (row >= M) continue;
                float val = acc[i][j][reg];
                if (mode == 0) {
                    float o = val + bv[c];
                    int b = row / LVTOT, pix = row - b * LVTOT;
                    int h = c >> 5, d = c & 31;
                    vperm[(((size_t)(b * NH + h)) * LVTOT + pix) * HD + d] = f2bf(o);
                } else {
                    if (c < 256) off_b[(size_t)row * 256 + c] = f2bf(val + boff[c]);
                    else awl_b[(size_t)row * 128 + (c - 256)] = f2bf(val + battn[c - 256]);
                }
            }
        }
    }
}

// ---------------------------------------------------------------------------
// GEMM3: sampled(bf16) @ Wo + bo -> out fp32
// ---------------------------------------------------------------------------
__global__ __launch_bounds__(256, 3) void gemm_out(
    const ushort_t* __restrict__ A, const ushort_t* __restrict__ BT,
    const float* __restrict__ bo, float* __restrict__ out)
{
    __shared__ ushort_t Asl[128 * 64];
    __shared__ ushort_t Bsl[128 * 64];

    const int m0 = (blockIdx.x % 263) * 128;
    const int n0 = (blockIdx.x / 263) * 128;
    const int M = 33600;

    f32x4 acc[4][4];
    #pragma unroll
    for (int i = 0; i < 4; i++)
        #pragma unroll
        for (int j = 0; j < 4; j++) acc[i][j] = (f32x4){0.f, 0.f, 0.f, 0.f};

    gemm_core(A, BT, M, m0, n0, Asl, Bsl, acc);

    const int tid  = threadIdx.x;
    const int wave = tid >> 6, lane = tid & 63;
    const int quad = lane >> 4, mr = lane & 15;
    const int wm   = (wave >> 1) * 64, wn = (wave & 1) * 64;

    #pragma unroll
    for (int i = 0; i < 4; i++) {
        const int rbase = m0 + wm + i * 16 + quad * 4;
        #pragma unroll
        for (int j = 0; j < 4; j++) {
            const int c = n0 + wn + j * 16 + mr;
            #pragma unroll
            for (int reg = 0; reg < 4; reg++) {
                int row = rbase + reg;
                if (row >= M) continue;
                out[(size_t)row * 256 + c] = acc[i][j][reg] + bo[c];
            }
        }
    }
}

// ---------------------------------------------------------------------------
// Sampler v7: plane-locality blocks. block = (b, h, 32-query chunk); with
// round-robin block->XCD dispatch, h = bid&7 pins each head's planes to one
// XCD (per-XCD working set = 4 planes = 2.2 MB bf16 < 4 MB L2). Gathers are
// saddr-form (uniform plane base SGPR + 32-bit voffset). bf16 vperm halves
// cache-side gather traffic vs fp32.
// Wave = 8 queries x (8 lanes x 4 dims). LDS w/iv padded [pt][33].
// ---------------------------------------------------------------------------
__global__ __launch_bounds__(256) void msda_sample(
    const ushort_t* __restrict__ vperm, const ushort_t* __restrict__ off,
    const ushort_t* __restrict__ awl, const float* __restrict__ refp,
    ushort_t* __restrict__ sampled)
{
    __shared__ float4 s_w[16 * 33];   // [lp][ql], pad 33 vs 32
    __shared__ int4   s_i[16 * 33];

    const int tid = threadIdx.x;
    const int bid = blockIdx.x;
    const int h   = bid & 7;          // XCD-pinned head
    const int r   = bid >> 3;         // 0..1051
    const int b   = r / 263;
    const int c   = r - b * 263;      // chunk within batch
    const int q0b = c * 32;           // first query (within batch b)
    const int bq0 = b * LQ + q0b;

    const int Hs[4]   = {80, 40, 20, 10};
    const int base[4] = {0, 6400, 8000, 8400};

    #pragma unroll
    for (int it = 0; it < 2; it++) {
        const int s  = it * 256 + tid;
        const int ql = s >> 4, lp = s & 15;
        const int l  = lp >> 2;
        const int qv = (q0b + ql < LQ) ? ql : 0;   // clamp tail chunk reads
        const size_t bq = (size_t)(bq0 + qv);
        const int Wl = Hs[l];

        unsigned od = *(const unsigned*)(off + bq * 256 + h * 32 + lp * 2);
        float ox = bflo(od), oy = bfhi(od);
        float lgt = bflo((unsigned)awl[bq * 128 + h * 16 + lp]);
        // softmax over the 16-lane (q) group, no max pass (bounded logits)
        float e = __expf(lgt);
        float sum = e;
        sum += __shfl_xor(sum, 1, 16);
        sum += __shfl_xor(sum, 2, 16);
        sum += __shfl_xor(sum, 4, 16);
        sum += __shfl_xor(sum, 8, 16);
        float aw = e * __builtin_amdgcn_rcpf(sum);

        float2 rp = *(const float2*)(refp + bq * 8 + l * 2);
        float x = rp.x * (float)Wl + ox - 0.5f;
        float y = rp.y * (float)Wl + oy - 0.5f;
        float x0f = floorf(x), y0f = floorf(y);
        float wx = x - x0f, wy = y - y0f;
        int x0 = (int)x0f, y0 = (int)y0f;
        bool vx0 = (x0 >= 0) & (x0 < Wl);
        bool vx1 = (x0 + 1 >= 0) & (x0 + 1 < Wl);
        bool vy0 = (y0 >= 0) & (y0 < Wl);
        bool vy1 = (y0 + 1 >= 0) & (y0 + 1 < Wl);
        int cx0 = min(max(x0, 0), Wl - 1);
        int cx1 = min(max(x0 + 1, 0), Wl - 1);
        int cy0 = min(max(y0, 0), Wl - 1);
        int cy1 = min(max(y0 + 1, 0), Wl - 1);
        float w00 = (vx0 && vy0) ? (1.f - wx) * (1.f - wy) * aw : 0.f;
        float w01 = (vx1 && vy0) ? wx * (1.f - wy) * aw : 0.f;
        float w10 = (vx0 && vy1) ? (1.f - wx) * wy * aw : 0.f;
        float w11 = (vx1 && vy1) ? wx * wy * aw : 0.f;
        const int rec = lp * 33 + ql;
        s_w[rec] = make_float4(w00, w01, w10, w11);
        s_i[rec] = make_int4((base[l] + cy0 * Wl + cx0) << 6,
                             (base[l] + cy0 * Wl + cx1) << 6,
                             (base[l] + cy1 * Wl + cx0) << 6,
                             (base[l] + cy1 * Wl + cx1) << 6);
    }
    __syncthreads();

    const int ql  = tid >> 3;          // 0..31
    const int l8  = tid & 7;
    const int dby = l8 * 8;            // byte offset of this lane's 4 dims

    if (q0b + ql < LQ) {
        // uniform (SGPR) plane base: one (b,h) plane, 544 KB bf16
        const char* plane = (const char*)(vperm + (size_t)(b * NH + h) * (LVTOT * HD));
        f32x2 a01 = (f32x2){0.f, 0.f};
        f32x2 a23 = (f32x2){0.f, 0.f};
        #pragma unroll
        for (int pt = 0; pt < 16; pt++) {
            const int rec = pt * 33 + ql;
            float4 w  = s_w[rec];
            int4   iv = s_i[rec];
            uint2 v0 = *(const uint2*)(plane + (unsigned)(iv.x + dby));
            uint2 v1 = *(const uint2*)(plane + (unsigned)(iv.y + dby));
            uint2 v2 = *(const uint2*)(plane + (unsigned)(iv.z + dby));
            uint2 v3 = *(const uint2*)(plane + (unsigned)(iv.w + dby));
            f32x2 wx2 = (f32x2){w.x, w.x};
            f32x2 wy2 = (f32x2){w.y, w.y};
            f32x2 wz2 = (f32x2){w.z, w.z};
            f32x2 ww2 = (f32x2){w.w, w.w};
            a01 = __builtin_elementwise_fma(wx2, up2(v0.x), a01);
            a01 = __builtin_elementwise_fma(wy2, up2(v1.x), a01);
            a01 = __builtin_elementwise_fma(wz2, up2(v2.x), a01);
            a01 = __builtin_elementwise_fma(ww2, up2(v3.x), a01);
            a23 = __builtin_elementwise_fma(wx2, up2(v0.y), a23);
            a23 = __builtin_elementwise_fma(wy2, up2(v1.y), a23);
            a23 = __builtin_elementwise_fma(wz2, up2(v2.y), a23);
            a23 = __builtin_elementwise_fma(ww2, up2(v3.y), a23);
        }
        const size_t bq = (size_t)(bq0 + ql);
        ushort4 o;
        o.x = f2bf(a01[0]); o.y = f2bf(a01[1]);
        o.z = f2bf(a23[0]); o.w = f2bf(a23[1]);
        *(ushort4*)(sampled + bq * 256 + h * 32 + l8 * 4) = o;
    }
}

extern "C" void kernel_launch(void* const* d_in, const int* in_sizes, int n_in,
                              void* d_out, int out_size, void* d_ws, size_t ws_size,
                              hipStream_t stream) {
    const float* query = (const float*)d_in[0];
    const float* refp  = (const float*)d_in[1];
    const float* value = (const float*)d_in[2];
    const float* Wv    = (const float*)d_in[4];
    const float* bv    = (const float*)d_in[5];
    const float* Woff  = (const float*)d_in[6];
    const float* boff  = (const float*)d_in[7];
    const float* Wattn = (const float*)d_in[8];
    const float* battn = (const float*)d_in[9];
    const float* Wo    = (const float*)d_in[10];
    const float* bo    = (const float*)d_in[11];
    float* out = (float*)d_out;

    ushort_t* ws = (ushort_t*)d_ws;
    ushort_t* off_b   = ws;                       // 33600*256
    ushort_t* awl_b   = off_b + 8601600;          // 33600*128
    ushort_t* value_b = awl_b + 4300800;          // 34000*256
    ushort_t* query_b = value_b + 8704000;        // 33600*256 (aliased w/ sampled)
    ushort_t* vperm_b = query_b + 8601600;        // 34000*256 (bf16)
    ushort_t* BT      = vperm_b + 8704000;        // 896*256
    ushort_t* sampled_b = query_b;                // alias: query dead after gemm_fused

    prep_all<<<dim3(17796), 256, 0, stream>>>(
        value, query, Wv, Woff, Wattn, Wo, value_b, query_b, BT);

    gemm_fused<<<dim3(532 + 789), 256, 0, stream>>>(
        value_b, query_b, BT, bv, boff, battn, vperm_b, off_b, awl_b);

    msda_sample<<<dim3(8 * 4 * 263), 256, 0, stream>>>(
        vperm_b, off_b, awl_b, refp, sampled_b);

    gemm_out<<<dim3(526), 256, 0, stream>>>(
        sampled_b, BT + 163840, bo, out);
}

// Round 4
// 248.095 us; speedup vs baseline: 1.0706x; 1.0008x over previous
//
#include <hip/hip_runtime.h>
#include <math.h>

#define BB 4
#define LQ 8400
#define NH 8
#define LVTOT 8500
#define HD 32

typedef __attribute__((ext_vector_type(8))) short short8;
typedef __attribute__((ext_vector_type(4))) float f32x4;
typedef __attribute__((ext_vector_type(2))) float f32x2;
typedef __attribute__((ext_vector_type(2))) _Float16 half2_t;
typedef __attribute__((ext_vector_type(2))) __fp16 fp16x2_t;
typedef unsigned short ushort_t;

__device__ __forceinline__ ushort_t f2bf(float f) {
    union { float f; unsigned u; } v; v.f = f;
    unsigned r = v.u + 0x7fffu + ((v.u >> 16) & 1u);   // RNE
    return (ushort_t)(r >> 16);
}
__device__ __forceinline__ float bflo(unsigned u) {
    union { unsigned u; float f; } x; x.u = u << 16; return x.f;
}
__device__ __forceinline__ float bfhi(unsigned u) {
    union { unsigned u; float f; } x; x.u = u & 0xffff0000u; return x.f;
}
__device__ __forceinline__ half2_t ash2(unsigned u) {
    union { unsigned u; half2_t h; } x; x.u = u; return x.h;
}
__device__ __forceinline__ unsigned pk2u(fp16x2_t h) {
    union { fp16x2_t h; unsigned u; } x; x.h = h; return x.u;
}

// async global->LDS DMA, 16 B per lane (wave-uniform LDS base + lane*16)
__device__ __forceinline__ void dma16(const ushort_t* g, ushort_t* l) {
    __builtin_amdgcn_global_load_lds(
        (const __attribute__((address_space(1))) void*)g,
        (__attribute__((address_space(3))) void*)l, 16, 0, 0);
}

// ---------------------------------------------------------------------------
// Merged prep: blocks [0,8500) cast value, [8500,16900) cast query,
// [16900,17796) build BT (transposed bf16 weights, 896 rows x 256 k:
// rows 0..255 = Wv^T, 256..639 = [Woff|Wattn]^T, 640..895 = Wo^T).
// ---------------------------------------------------------------------------
__global__ __launch_bounds__(256) void prep_all(
    const float* __restrict__ value, const float* __restrict__ query,
    const float* __restrict__ Wv, const float* __restrict__ Woff,
    const float* __restrict__ Wattn, const float* __restrict__ Wo,
    ushort_t* __restrict__ value_b, ushort_t* __restrict__ query_b,
    ushort_t* __restrict__ BT)
{
    const int bid = blockIdx.x;
    if (bid < 16900) {
        const float* src = (bid < 8500) ? value : query;
        ushort_t* dst = (bid < 8500) ? value_b : query_b;
        int i = (bid < 8500 ? bid : bid - 8500) * 256 + threadIdx.x;
        float4 f = ((const float4*)src)[i];
        ushort4 o;
        o.x = f2bf(f.x); o.y = f2bf(f.y); o.z = f2bf(f.z); o.w = f2bf(f.w);
        ((ushort4*)dst)[i] = o;
    } else {
        int idx = (bid - 16900) * 256 + threadIdx.x;   // 896*256
        int r = idx >> 8, k = idx & 255;
        float v;
        if (r < 256) v = Wv[k * 256 + r];
        else if (r < 640) {
            int n = r - 256;
            v = (n < 256) ? Woff[k * 256 + n] : Wattn[k * 128 + (n - 256)];
        } else v = Wo[k * 256 + (r - 640)];
        BT[idx] = f2bf(v);
    }
}

// ---------------------------------------------------------------------------
// Shared GEMM core: 128x128 tile, 4 waves, BK=64. Staging via global_load_lds
// dwordx4; XOR swizzle on the GLOBAL segment so linear DMA placement yields
// physical seg = logical ^ (row&7).
// ---------------------------------------------------------------------------
__device__ __forceinline__ void gemm_core(
    const ushort_t* __restrict__ A, const ushort_t* __restrict__ B, int M,
    int m0, int n0, ushort_t* Asl, ushort_t* Bsl, f32x4 acc[4][4])
{
    const int tid  = threadIdx.x;
    const int wave = tid >> 6, lane = tid & 63;
    const int quad = lane >> 4, mr = lane & 15;
    const int wm   = (wave >> 1) * 64, wn = (wave & 1) * 64;
    const int oct  = lane >> 3;       // 0..7 row-in-wave-slab
    const int bseg = lane & 7;        // physical 16B slot within row

    for (int k0 = 0; k0 < 256; k0 += 64) {
        __syncthreads();              // prior iteration's reads done
        #pragma unroll
        for (int i = 0; i < 4; i++) {
            int m  = i * 32 + wave * 8 + oct;          // block-relative row
            int gs = bseg ^ (m & 7);                   // swizzled source seg
            int am = min(m0 + m, M - 1);
            dma16(A + (size_t)am * 256 + k0 + gs * 8,
                  Asl + (size_t)(i * 32 + wave * 8) * 64 + lane * 8);
            int bn = n0 + m;
            dma16(B + (size_t)bn * 256 + k0 + gs * 8,
                  Bsl + (size_t)(i * 32 + wave * 8) * 64 + lane * 8);
        }
        __syncthreads();              // DMA landed
        #pragma unroll
        for (int ks = 0; ks < 2; ks++) {
            short8 af[4], bf[4];
            const int ksl = ks * 4 + quad;
            #pragma unroll
            for (int i = 0; i < 4; i++) {
                int m = wm + i * 16 + mr;
                af[i] = *(const short8*)&Asl[m * 64 + (ksl ^ (m & 7)) * 8];
                int n = wn + i * 16 + mr;
                bf[i] = *(const short8*)&Bsl[n * 64 + (ksl ^ (n & 7)) * 8];
            }
            #pragma unroll
            for (int i = 0; i < 4; i++)
                #pragma unroll
                for (int j = 0; j < 4; j++)
                    acc[i][j] = __builtin_amdgcn_mfma_f32_16x16x32_bf16(
                        af[i], bf[j], acc[i][j], 0, 0, 0);
        }
    }
}

// ---------------------------------------------------------------------------
// Fused GEMM1 (value->vperm f16, 532 blocks) + GEMM2 (query->off/awl, 789).
// Block-id swizzle: column tiles of the same A row-panel are ADJACENT bids,
// so the A re-read for n-tile 1/2 hits L2/L3 right after the first touch.
// ---------------------------------------------------------------------------
__global__ __launch_bounds__(256, 3) void gemm_fused(
    const ushort_t* __restrict__ Av, const ushort_t* __restrict__ Aq,
    const ushort_t* __restrict__ BT,
    const float* __restrict__ bv, const float* __restrict__ boff,
    const float* __restrict__ battn,
    ushort_t* __restrict__ vperm, ushort_t* __restrict__ off_b,
    ushort_t* __restrict__ awl_b)
{
    __shared__ ushort_t Asl[128 * 64];
    __shared__ ushort_t Bsl[128 * 64];

    const int bid = blockIdx.x;
    int mode, m0, n0, M;
    const ushort_t *A, *B;
    if (bid < 532) { mode = 0; m0 = (bid >> 1) * 128; n0 = (bid & 1) * 128;
                     A = Av; B = BT; M = 34000; }
    else { int b2 = bid - 532;
           mode = 1; m0 = (b2 / 3) * 128; n0 = (b2 % 3) * 128;
           A = Aq; B = BT + 65536; M = 33600; }

    f32x4 acc[4][4];
    #pragma unroll
    for (int i = 0; i < 4; i++)
        #pragma unroll
        for (int j = 0; j < 4; j++) acc[i][j] = (f32x4){0.f, 0.f, 0.f, 0.f};

    gemm_core(A, B, M, m0, n0, Asl, Bsl, acc);

    const int tid  = threadIdx.x;
    const int wave = tid >> 6, lane = tid & 63;
    const int quad = lane >> 4, mr = lane & 15;
    const int wm   = (wave >> 1) * 64, wn = (wave & 1) * 64;

    #pragma unroll
    for (int i = 0; i < 4; i++) {
        const int rbase = m0 + wm + i * 16 + quad * 4;
        #pragma unroll
        for (int j = 0; j < 4; j++) {
            const int c = n0 + wn + j * 16 + mr;
            #pragma unroll
            for (int reg = 0; reg < 4; reg++) {
                int row = rbase + reg;
                if (row >= M) continue;
                float val = acc[i][j][reg];
                if (mode == 0) {
                    float o = val + bv[c];
                    int b = row / LVTOT, pix = row - b * LVTOT;
                    int h = c >> 5, d = c & 31;
                    union { _Float16 h16; ushort_t u; } cv;
                    cv.h16 = (_Float16)o;                       // f16 plane
                    vperm[(((size_t)(b * NH + h)) * LVTOT + pix) * HD + d] = cv.u;
                } else {
                    if (c < 256) off_b[(size_t)row * 256 + c] = f2bf(val + boff[c]);
                    else awl_b[(size_t)row * 128 + (c - 256)] = f2bf(val + battn[c - 256]);
                }
            }
        }
    }
}

// ---------------------------------------------------------------------------
// GEMM3: sampled(bf16) @ Wo + bo -> out fp32
// ---------------------------------------------------------------------------
__global__ __launch_bounds__(256, 3) void gemm_out(
    const ushort_t* __restrict__ A, const ushort_t* __restrict__ BT,
    const float* __restrict__ bo, float* __restrict__ out)
{
    __shared__ ushort_t Asl[128 * 64];
    __shared__ ushort_t Bsl[128 * 64];

    const int m0 = (blockIdx.x >> 1) * 128;    // adjacency swizzle (263x2)
    const int n0 = (blockIdx.x & 1) * 128;
    const int M = 33600;

    f32x4 acc[4][4];
    #pragma unroll
    for (int i = 0; i < 4; i++)
        #pragma unroll
        for (int j = 0; j < 4; j++) acc[i][j] = (f32x4){0.f, 0.f, 0.f, 0.f};

    gemm_core(A, BT, M, m0, n0, Asl, Bsl, acc);

    const int tid  = threadIdx.x;
    const int wave = tid >> 6, lane = tid & 63;
    const int quad = lane >> 4, mr = lane & 15;
    const int wm   = (wave >> 1) * 64, wn = (wave & 1) * 64;

    #pragma unroll
    for (int i = 0; i < 4; i++) {
        const int rbase = m0 + wm + i * 16 + quad * 4;
        #pragma unroll
        for (int j = 0; j < 4; j++) {
            const int c = n0 + wn + j * 16 + mr;
            #pragma unroll
            for (int reg = 0; reg < 4; reg++) {
                int row = rbase + reg;
                if (row >= M) continue;
                out[(size_t)row * 256 + c] = acc[i][j][reg] + bo[c];
            }
        }
    }
}

// ---------------------------------------------------------------------------
// Sampler v8: plane-locality blocks (b, h, 32-query chunk), h = bid&7 XCD-
// pinned. f16 plane; phase 1 packs bilinear weights as two f16x2 pairs;
// phase 2 runs 4-point groups (16 gathers in flight) and consumes via
// v_perm_b32 corner-pairing + v_dot2_f32_f16 (8 perm + 8 dot2 per point,
// replacing 16 unpack + 8 pk_fma).
// ---------------------------------------------------------------------------
__global__ __launch_bounds__(256) void msda_sample(
    const ushort_t* __restrict__ vperm, const ushort_t* __restrict__ off,
    const ushort_t* __restrict__ awl, const float* __restrict__ refp,
    ushort_t* __restrict__ sampled)
{
    __shared__ uint2 s_w[16 * 33];   // (w00,w01) | (w10,w11) f16x2 pairs
    __shared__ int4  s_i[16 * 33];   // corner byte offsets within plane

    const int tid = threadIdx.x;
    const int bid = blockIdx.x;
    const int h   = bid & 7;          // XCD-pinned head
    const int r   = bid >> 3;         // 0..1051
    const int b   = r / 263;
    const int c   = r - b * 263;      // chunk within batch
    const int q0b = c * 32;           // first query (within batch b)
    const int bq0 = b * LQ + q0b;

    const int Hs[4]   = {80, 40, 20, 10};
    const int base[4] = {0, 6400, 8000, 8400};

    #pragma unroll
    for (int it = 0; it < 2; it++) {
        const int s  = it * 256 + tid;
        const int ql = s >> 4, lp = s & 15;
        const int l  = lp >> 2;
        const int qv = (q0b + ql < LQ) ? ql : 0;   // clamp tail chunk reads
        const size_t bq = (size_t)(bq0 + qv);
        const int Wl = Hs[l];

        unsigned od = *(const unsigned*)(off + bq * 256 + h * 32 + lp * 2);
        float ox = bflo(od), oy = bfhi(od);
        float lgt = bflo((unsigned)awl[bq * 128 + h * 16 + lp]);
        // softmax over the 16-lane (q) group, no max pass (bounded logits)
        float e = __expf(lgt);
        float sum = e;
        sum += __shfl_xor(sum, 1, 16);
        sum += __shfl_xor(sum, 2, 16);
        sum += __shfl_xor(sum, 4, 16);
        sum += __shfl_xor(sum, 8, 16);
        float aw = e * __builtin_amdgcn_rcpf(sum);

        float2 rp = *(const float2*)(refp + bq * 8 + l * 2);
        float x = rp.x * (float)Wl + ox - 0.5f;
        float y = rp.y * (float)Wl + oy - 0.5f;
        float x0f = floorf(x), y0f = floorf(y);
        float wx = x - x0f, wy = y - y0f;
        int x0 = (int)x0f, y0 = (int)y0f;
        bool vx0 = (x0 >= 0) & (x0 < Wl);
        bool vx1 = (x0 + 1 >= 0) & (x0 + 1 < Wl);
        bool vy0 = (y0 >= 0) & (y0 < Wl);
        bool vy1 = (y0 + 1 >= 0) & (y0 + 1 < Wl);
        int cx0 = min(max(x0, 0), Wl - 1);
        int cx1 = min(max(x0 + 1, 0), Wl - 1);
        int cy0 = min(max(y0, 0), Wl - 1);
        int cy1 = min(max(y0 + 1, 0), Wl - 1);
        float w00 = (vx0 && vy0) ? (1.f - wx) * (1.f - wy) * aw : 0.f;
        float w01 = (vx1 && vy0) ? wx * (1.f - wy) * aw : 0.f;
        float w10 = (vx0 && vy1) ? (1.f - wx) * wy * aw : 0.f;
        float w11 = (vx1 && vy1) ? wx * wy * aw : 0.f;
        const int rec = lp * 33 + ql;
        s_w[rec] = make_uint2(pk2u(__builtin_amdgcn_cvt_pkrtz(w00, w01)),
                              pk2u(__builtin_amdgcn_cvt_pkrtz(w10, w11)));
        s_i[rec] = make_int4((base[l] + cy0 * Wl + cx0) << 6,
                             (base[l] + cy0 * Wl + cx1) << 6,
                             (base[l] + cy1 * Wl + cx0) << 6,
                             (base[l] + cy1 * Wl + cx1) << 6);
    }
    __syncthreads();

    const int ql  = tid >> 3;          // 0..31
    const int l8  = tid & 7;
    const int dby = l8 * 8;            // byte offset of this lane's 4 dims

    if (q0b + ql < LQ) {
        // uniform (SGPR) plane base: one (b,h) plane, 544 KB f16
        const char* plane = (const char*)(vperm + (size_t)(b * NH + h) * (LVTOT * HD));
        float a0 = 0.f, a1 = 0.f, a2 = 0.f, a3 = 0.f;
        #pragma unroll
        for (int pg = 0; pg < 4; pg++) {
            uint2 wv[4]; int4 iv[4];
            #pragma unroll
            for (int t = 0; t < 4; t++) {
                const int rec = (pg * 4 + t) * 33 + ql;
                wv[t] = s_w[rec];
                iv[t] = s_i[rec];
            }
            uint2 g0[4], g1[4], g2[4], g3[4];
            #pragma unroll
            for (int t = 0; t < 4; t++) {
                g0[t] = *(const uint2*)(plane + (unsigned)(iv[t].x + dby));
                g1[t] = *(const uint2*)(plane + (unsigned)(iv[t].y + dby));
                g2[t] = *(const uint2*)(plane + (unsigned)(iv[t].z + dby));
                g3[t] = *(const uint2*)(plane + (unsigned)(iv[t].w + dby));
            }
            #pragma unroll
            for (int t = 0; t < 4; t++) {
                half2_t w01 = ash2(wv[t].x);    // (w00, w01)
                half2_t w23 = ash2(wv[t].y);    // (w10, w11)
                // dims 0,1 (the .x words): pair corners (c00,c01) and (c10,c11)
                unsigned p01lo = __builtin_amdgcn_perm(g1[t].x, g0[t].x, 0x05040100);
                unsigned p01hi = __builtin_amdgcn_perm(g1[t].x, g0[t].x, 0x07060302);
                unsigned p23lo = __builtin_amdgcn_perm(g3[t].x, g2[t].x, 0x05040100);
                unsigned p23hi = __builtin_amdgcn_perm(g3[t].x, g2[t].x, 0x07060302);
                a0 = __builtin_amdgcn_fdot2(w01, ash2(p01lo), a0, false);
                a0 = __builtin_amdgcn_fdot2(w23, ash2(p23lo), a0, false);
                a1 = __builtin_amdgcn_fdot2(w01, ash2(p01hi), a1, false);
                a1 = __builtin_amdgcn_fdot2(w23, ash2(p23hi), a1, false);
                // dims 2,3 (the .y words)
                unsigned q01lo = __builtin_amdgcn_perm(g1[t].y, g0[t].y, 0x05040100);
                unsigned q01hi = __builtin_amdgcn_perm(g1[t].y, g0[t].y, 0x07060302);
                unsigned q23lo = __builtin_amdgcn_perm(g3[t].y, g2[t].y, 0x05040100);
                unsigned q23hi = __builtin_amdgcn_perm(g3[t].y, g2[t].y, 0x07060302);
                a2 = __builtin_amdgcn_fdot2(w01, ash2(q01lo), a2, false);
                a2 = __builtin_amdgcn_fdot2(w23, ash2(q23lo), a2, false);
                a3 = __builtin_amdgcn_fdot2(w01, ash2(q01hi), a3, false);
                a3 = __builtin_amdgcn_fdot2(w23, ash2(q23hi), a3, false);
            }
        }
        const size_t bq = (size_t)(bq0 + ql);
        ushort4 o;
        o.x = f2bf(a0); o.y = f2bf(a1);
        o.z = f2bf(a2); o.w = f2bf(a3);
        *(ushort4*)(sampled + bq * 256 + h * 32 + l8 * 4) = o;
    }
}

extern "C" void kernel_launch(void* const* d_in, const int* in_sizes, int n_in,
                              void* d_out, int out_size, void* d_ws, size_t ws_size,
                              hipStream_t stream) {
    const float* query = (const float*)d_in[0];
    const float* refp  = (const float*)d_in[1];
    const float* value = (const float*)d_in[2];
    const float* Wv    = (const float*)d_in[4];
    const float* bv    = (const float*)d_in[5];
    const float* Woff  = (const float*)d_in[6];
    const float* boff  = (const float*)d_in[7];
    const float* Wattn = (const float*)d_in[8];
    const float* battn = (const float*)d_in[9];
    const float* Wo    = (const float*)d_in[10];
    const float* bo    = (const float*)d_in[11];
    float* out = (float*)d_out;

    ushort_t* ws = (ushort_t*)d_ws;
    ushort_t* off_b   = ws;                       // 33600*256
    ushort_t* awl_b   = off_b + 8601600;          // 33600*128
    ushort_t* value_b = awl_b + 4300800;          // 34000*256
    ushort_t* query_b = value_b + 8704000;        // 33600*256 (aliased w/ sampled)
    ushort_t* vperm_b = query_b + 8601600;        // 34000*256 (f16)
    ushort_t* BT      = vperm_b + 8704000;        // 896*256
    ushort_t* sampled_b = query_b;                // alias: query dead after gemm_fused

    prep_all<<<dim3(17796), 256, 0, stream>>>(
        value, query, Wv, Woff, Wattn, Wo, value_b, query_b, BT);

    gemm_fused<<<dim3(532 + 789), 256, 0, stream>>>(
        value_b, query_b, BT, bv, boff, battn, vperm_b, off_b, awl_b);

    msda_sample<<<dim3(8 * 4 * 263), 256, 0, stream>>>(
        vperm_b, off_b, awl_b, refp, sampled_b);

    gemm_out<<<dim3(526), 256, 0, stream>>>(
        sampled_b, BT + 163840, bo, out);
}

// Round 5
// 248.073 us; speedup vs baseline: 1.0707x; 1.0001x over previous
//
#include <hip/hip_runtime.h>
#include <math.h>

#define BB 4
#define LQ 8400
#define NH 8
#define LVTOT 8500
#define HD 32
#define NQB 525      // queries per sampler block (16 chunks x 525 = 8400)

typedef __attribute__((ext_vector_type(8))) short short8;
typedef __attribute__((ext_vector_type(4))) float f32x4;
typedef __attribute__((ext_vector_type(2))) float f32x2;
typedef __attribute__((ext_vector_type(2))) _Float16 half2_t;
typedef __attribute__((ext_vector_type(2))) __fp16 fp16x2_t;
typedef unsigned short ushort_t;

__device__ __forceinline__ ushort_t f2bf(float f) {
    union { float f; unsigned u; } v; v.f = f;
    unsigned r = v.u + 0x7fffu + ((v.u >> 16) & 1u);   // RNE
    return (ushort_t)(r >> 16);
}
__device__ __forceinline__ float bflo(unsigned u) {
    union { unsigned u; float f; } x; x.u = u << 16; return x.f;
}
__device__ __forceinline__ float bfhi(unsigned u) {
    union { unsigned u; float f; } x; x.u = u & 0xffff0000u; return x.f;
}
__device__ __forceinline__ half2_t ash2(unsigned u) {
    union { unsigned u; half2_t h; } x; x.u = u; return x.h;
}
__device__ __forceinline__ unsigned pk2u(fp16x2_t h) {
    union { fp16x2_t h; unsigned u; } x; x.h = h; return x.u;
}

// async global->LDS DMA, 16 B per lane (wave-uniform LDS base + lane*16)
__device__ __forceinline__ void dma16(const ushort_t* g, ushort_t* l) {
    __builtin_amdgcn_global_load_lds(
        (const __attribute__((address_space(1))) void*)g,
        (__attribute__((address_space(3))) void*)l, 16, 0, 0);
}

// ---------------------------------------------------------------------------
// Merged prep: blocks [0,8500) cast value, [8500,16900) cast query,
// [16900,17796) build BT (transposed bf16 weights, 896 rows x 256 k).
// ---------------------------------------------------------------------------
__global__ __launch_bounds__(256) void prep_all(
    const float* __restrict__ value, const float* __restrict__ query,
    const float* __restrict__ Wv, const float* __restrict__ Woff,
    const float* __restrict__ Wattn, const float* __restrict__ Wo,
    ushort_t* __restrict__ value_b, ushort_t* __restrict__ query_b,
    ushort_t* __restrict__ BT)
{
    const int bid = blockIdx.x;
    if (bid < 16900) {
        const float* src = (bid < 8500) ? value : query;
        ushort_t* dst = (bid < 8500) ? value_b : query_b;
        int i = (bid < 8500 ? bid : bid - 8500) * 256 + threadIdx.x;
        float4 f = ((const float4*)src)[i];
        ushort4 o;
        o.x = f2bf(f.x); o.y = f2bf(f.y); o.z = f2bf(f.z); o.w = f2bf(f.w);
        ((ushort4*)dst)[i] = o;
    } else {
        int idx = (bid - 16900) * 256 + threadIdx.x;   // 896*256
        int r = idx >> 8, k = idx & 255;
        float v;
        if (r < 256) v = Wv[k * 256 + r];
        else if (r < 640) {
            int n = r - 256;
            v = (n < 256) ? Woff[k * 256 + n] : Wattn[k * 128 + (n - 256)];
        } else v = Wo[k * 256 + (r - 640)];
        BT[idx] = f2bf(v);
    }
}

// ---------------------------------------------------------------------------
// Shared GEMM core: 128x128 tile, 4 waves, BK=64. Staging via global_load_lds
// dwordx4; XOR swizzle on the GLOBAL segment so linear DMA placement yields
// physical seg = logical ^ (row&7).
// ---------------------------------------------------------------------------
__device__ __forceinline__ void gemm_core(
    const ushort_t* __restrict__ A, const ushort_t* __restrict__ B, int M,
    int m0, int n0, ushort_t* Asl, ushort_t* Bsl, f32x4 acc[4][4])
{
    const int tid  = threadIdx.x;
    const int wave = tid >> 6, lane = tid & 63;
    const int quad = lane >> 4, mr = lane & 15;
    const int wm   = (wave >> 1) * 64, wn = (wave & 1) * 64;
    const int oct  = lane >> 3;       // 0..7 row-in-wave-slab
    const int bseg = lane & 7;        // physical 16B slot within row

    for (int k0 = 0; k0 < 256; k0 += 64) {
        __syncthreads();              // prior iteration's reads done
        #pragma unroll
        for (int i = 0; i < 4; i++) {
            int m  = i * 32 + wave * 8 + oct;          // block-relative row
            int gs = bseg ^ (m & 7);                   // swizzled source seg
            int am = min(m0 + m, M - 1);
            dma16(A + (size_t)am * 256 + k0 + gs * 8,
                  Asl + (size_t)(i * 32 + wave * 8) * 64 + lane * 8);
            int bn = n0 + m;
            dma16(B + (size_t)bn * 256 + k0 + gs * 8,
                  Bsl + (size_t)(i * 32 + wave * 8) * 64 + lane * 8);
        }
        __syncthreads();              // DMA landed
        #pragma unroll
        for (int ks = 0; ks < 2; ks++) {
            short8 af[4], bf[4];
            const int ksl = ks * 4 + quad;
            #pragma unroll
            for (int i = 0; i < 4; i++) {
                int m = wm + i * 16 + mr;
                af[i] = *(const short8*)&Asl[m * 64 + (ksl ^ (m & 7)) * 8];
                int n = wn + i * 16 + mr;
                bf[i] = *(const short8*)&Bsl[n * 64 + (ksl ^ (n & 7)) * 8];
            }
            #pragma unroll
            for (int i = 0; i < 4; i++)
                #pragma unroll
                for (int j = 0; j < 4; j++)
                    acc[i][j] = __builtin_amdgcn_mfma_f32_16x16x32_bf16(
                        af[i], bf[j], acc[i][j], 0, 0, 0);
        }
    }
}

// ---------------------------------------------------------------------------
// Fused GEMM1 (value->vperm f16, 532 blocks) + GEMM2 (query->off/awl, 789).
// ---------------------------------------------------------------------------
__global__ __launch_bounds__(256, 3) void gemm_fused(
    const ushort_t* __restrict__ Av, const ushort_t* __restrict__ Aq,
    const ushort_t* __restrict__ BT,
    const float* __restrict__ bv, const float* __restrict__ boff,
    const float* __restrict__ battn,
    ushort_t* __restrict__ vperm, ushort_t* __restrict__ off_b,
    ushort_t* __restrict__ awl_b)
{
    __shared__ ushort_t Asl[128 * 64];
    __shared__ ushort_t Bsl[128 * 64];

    const int bid = blockIdx.x;
    int mode, m0, n0, M;
    const ushort_t *A, *B;
    if (bid < 532) { mode = 0; m0 = (bid >> 1) * 128; n0 = (bid & 1) * 128;
                     A = Av; B = BT; M = 34000; }
    else { int b2 = bid - 532;
           mode = 1; m0 = (b2 / 3) * 128; n0 = (b2 % 3) * 128;
           A = Aq; B = BT + 65536; M = 33600; }

    f32x4 acc[4][4];
    #pragma unroll
    for (int i = 0; i < 4; i++)
        #pragma unroll
        for (int j = 0; j < 4; j++) acc[i][j] = (f32x4){0.f, 0.f, 0.f, 0.f};

    gemm_core(A, B, M, m0, n0, Asl, Bsl, acc);

    const int tid  = threadIdx.x;
    const int wave = tid >> 6, lane = tid & 63;
    const int quad = lane >> 4, mr = lane & 15;
    const int wm   = (wave >> 1) * 64, wn = (wave & 1) * 64;

    #pragma unroll
    for (int i = 0; i < 4; i++) {
        const int rbase = m0 + wm + i * 16 + quad * 4;
        #pragma unroll
        for (int j = 0; j < 4; j++) {
            const int c = n0 + wn + j * 16 + mr;
            #pragma unroll
            for (int reg = 0; reg < 4; reg++) {
                int row = rbase + reg;
                if (row >= M) continue;
                float val = acc[i][j][reg];
                if (mode == 0) {
                    float o = val + bv[c];
                    int b = row / LVTOT, pix = row - b * LVTOT;
                    int h = c >> 5, d = c & 31;
                    union { _Float16 h16; ushort_t u; } cv;
                    cv.h16 = (_Float16)o;                       // f16 plane
                    vperm[(((size_t)(b * NH + h)) * LVTOT + pix) * HD + d] = cv.u;
                } else {
                    if (c < 256) off_b[(size_t)row * 256 + c] = f2bf(val + boff[c]);
                    else awl_b[(size_t)row * 128 + (c - 256)] = f2bf(val + battn[c - 256]);
                }
            }
        }
    }
}

// ---------------------------------------------------------------------------
// GEMM3: sampled(bf16) @ Wo + bo -> out fp32
// ---------------------------------------------------------------------------
__global__ __launch_bounds__(256, 3) void gemm_out(
    const ushort_t* __restrict__ A, const ushort_t* __restrict__ BT,
    const float* __restrict__ bo, float* __restrict__ out)
{
    __shared__ ushort_t Asl[128 * 64];
    __shared__ ushort_t Bsl[128 * 64];

    const int m0 = (blockIdx.x >> 1) * 128;    // adjacency swizzle (263x2)
    const int n0 = (blockIdx.x & 1) * 128;
    const int M = 33600;

    f32x4 acc[4][4];
    #pragma unroll
    for (int i = 0; i < 4; i++)
        #pragma unroll
        for (int j = 0; j < 4; j++) acc[i][j] = (f32x4){0.f, 0.f, 0.f, 0.f};

    gemm_core(A, BT, M, m0, n0, Asl, Bsl, acc);

    const int tid  = threadIdx.x;
    const int wave = tid >> 6, lane = tid & 63;
    const int quad = lane >> 4, mr = lane & 15;
    const int wm   = (wave >> 1) * 64, wn = (wave & 1) * 64;

    #pragma unroll
    for (int i = 0; i < 4; i++) {
        const int rbase = m0 + wm + i * 16 + quad * 4;
        #pragma unroll
        for (int j = 0; j < 4; j++) {
            const int c = n0 + wn + j * 16 + mr;
            #pragma unroll
            for (int reg = 0; reg < 4; reg++) {
                int row = rbase + reg;
                if (row >= M) continue;
                out[(size_t)row * 256 + c] = acc[i][j][reg] + bo[c];
            }
        }
    }
}

// ---------------------------------------------------------------------------
// Sampler v9: per-(b,h) mega-blocks with LDS-staged levels 1+2.
// Grid 512 = (chunk 0..15, b 0..3, h = bid&7 XCD-pinned), 1024 threads.
// Staging: l1+l2 planes (2000 px x 64 B = 125 KB) -> LDS once per block.
// 9 passes of 64 queries: phase1 (1 thread per (q,lp): softmax+weights ->
// s_w/s_iv), phase2 (16 lanes per q: 4 global pts (l0 | l3) + 4 LDS pts
// (l1 | l2), f16 perm+fdot2, shfl_xor(8) combine, 8-lane store).
// l0 stays in XCD-pinned L2 (4 planes = 1.6 MB); l3 (6.4 KB) is L1-hot.
// ---------------------------------------------------------------------------
__global__ __launch_bounds__(1024) void msda_sample(
    const ushort_t* __restrict__ vperm, const ushort_t* __restrict__ off,
    const ushort_t* __restrict__ awl, const float* __restrict__ refp,
    ushort_t* __restrict__ sampled)
{
    __shared__ ushort_t lds_v[2000 * HD];      // 128,000 B: l1 (0..1599), l2 (1600..1999)
    __shared__ uint2    s_w[64 * 17];          // (w00,w01)|(w10,w11) f16x2, stride 17
    __shared__ ushort4  s_iv[64 * 17];         // corner pixel indices

    const int tid   = threadIdx.x;
    const int bid   = blockIdx.x;
    const int h     = bid & 7;                 // XCD-pinned head
    const int b     = (bid >> 3) & 3;
    const int chunk = bid >> 5;                // 0..15
    const int q0    = chunk * NQB;             // first query in batch b
    const size_t bq0 = (size_t)b * LQ + q0;

    const ushort_t* plane = vperm + (size_t)(b * NH + h) * (LVTOT * HD);

    // ---- stage l1+l2 (pixels 6400..8399) into LDS: 8000 x 16 B ----
    {
        const ushort_t* psrc = plane + 6400 * HD;
        #pragma unroll
        for (int it = 0; it < 8; it++) {
            int i = it * 1024 + tid;
            if (i < 8000) dma16(psrc + i * 8, lds_v + i * 8);
        }
    }

    const int Hs[4]    = {80, 40, 20, 10};
    const int base2[4] = {0, 0, 1600, 8400};   // l0 raw, l1/l2 LDS-rebased, l3 raw

    const int NPASS = (NQB + 63) / 64;         // 9

    // ---------------- phase 1 for pass 0 ----------------
    {
        const int ql = tid >> 4, lp = tid & 15;
        const int l  = lp >> 2;
        const int lq = min(ql, NQB - 1);       // pass 0: q index = ql
        const size_t bq = bq0 + lq;
        const int Wl = Hs[l];

        unsigned od = *(const unsigned*)(off + bq * 256 + h * 32 + lp * 2);
        float ox = bflo(od), oy = bfhi(od);
        float lgt = bflo((unsigned)awl[bq * 128 + h * 16 + lp]);
        float e = __expf(lgt);
        float sum = e;
        sum += __shfl_xor(sum, 1, 16);
        sum += __shfl_xor(sum, 2, 16);
        sum += __shfl_xor(sum, 4, 16);
        sum += __shfl_xor(sum, 8, 16);
        float aw = e * __builtin_amdgcn_rcpf(sum);

        float2 rp = *(const float2*)(refp + bq * 8 + l * 2);
        float x = rp.x * (float)Wl + ox - 0.5f;
        float y = rp.y * (float)Wl + oy - 0.5f;
        float x0f = floorf(x), y0f = floorf(y);
        float wx = x - x0f, wy = y - y0f;
        int x0 = (int)x0f, y0 = (int)y0f;
        bool vx0 = (x0 >= 0) & (x0 < Wl);
        bool vx1 = (x0 + 1 >= 0) & (x0 + 1 < Wl);
        bool vy0 = (y0 >= 0) & (y0 < Wl);
        bool vy1 = (y0 + 1 >= 0) & (y0 + 1 < Wl);
        int cx0 = min(max(x0, 0), Wl - 1);
        int cx1 = min(max(x0 + 1, 0), Wl - 1);
        int cy0 = min(max(y0, 0), Wl - 1);
        int cy1 = min(max(y0 + 1, 0), Wl - 1);
        float w00 = (vx0 && vy0) ? (1.f - wx) * (1.f - wy) * aw : 0.f;
        float w01 = (vx1 && vy0) ? wx * (1.f - wy) * aw : 0.f;
        float w10 = (vx0 && vy1) ? (1.f - wx) * wy * aw : 0.f;
        float w11 = (vx1 && vy1) ? wx * wy * aw : 0.f;
        const int rec = ql * 17 + lp;
        const int bs = base2[l];
        s_w[rec] = make_uint2(pk2u(__builtin_amdgcn_cvt_pkrtz(w00, w01)),
                              pk2u(__builtin_amdgcn_cvt_pkrtz(w10, w11)));
        s_iv[rec] = make_ushort4((ushort_t)(bs + cy0 * Wl + cx0),
                                 (ushort_t)(bs + cy0 * Wl + cx1),
                                 (ushort_t)(bs + cy1 * Wl + cx0),
                                 (ushort_t)(bs + cy1 * Wl + cx1));
    }
    __syncthreads();   // staging landed + s_w/s_iv visible

    for (int p = 0; ; p++) {
        // ---------------- phase 2: pass p ----------------
        {
            const int ql  = tid >> 4;          // 0..63
            const int sub = tid & 15;
            const int g   = sub >> 3;          // 0: pts {0-3 glob,4-7 lds}; 1: {12-15 glob,8-11 lds}
            const int dsh = (sub & 7) * 4;     // ushort element offset of this lane's 4 dims
            const int dby = (sub & 7) * 8;     // byte offset
            const int lq  = p * 64 + ql;

            float a0 = 0.f, a1 = 0.f, a2 = 0.f, a3 = 0.f;

            // issue 4 global pts (l0 for g0, l3 for g1)
            uint2 gw[4]; ushort4 giv[4];
            uint2 gv0[4], gv1[4], gv2[4], gv3[4];
            #pragma unroll
            for (int pi = 0; pi < 4; pi++) {
                const int pt = g ? (12 + pi) : pi;
                const int rec = ql * 17 + pt;
                gw[pi]  = s_w[rec];
                giv[pi] = s_iv[rec];
                gv0[pi] = *(const uint2*)((const char*)plane + (((unsigned)giv[pi].x << 6) + dby));
                gv1[pi] = *(const uint2*)((const char*)plane + (((unsigned)giv[pi].y << 6) + dby));
                gv2[pi] = *(const uint2*)((const char*)plane + (((unsigned)giv[pi].z << 6) + dby));
                gv3[pi] = *(const uint2*)((const char*)plane + (((unsigned)giv[pi].w << 6) + dby));
            }
            // 4 LDS pts (l1 for g0, l2 for g1) — hides global latency
            #pragma unroll
            for (int pi = 0; pi < 4; pi++) {
                const int pt = g ? (8 + pi) : (4 + pi);
                const int rec = ql * 17 + pt;
                uint2 w = s_w[rec];
                ushort4 iv = s_iv[rec];
                uint2 v0 = *(const uint2*)&lds_v[(unsigned)iv.x * HD + dsh];
                uint2 v1 = *(const uint2*)&lds_v[(unsigned)iv.y * HD + dsh];
                uint2 v2 = *(const uint2*)&lds_v[(unsigned)iv.z * HD + dsh];
                uint2 v3 = *(const uint2*)&lds_v[(unsigned)iv.w * HD + dsh];
                half2_t w01 = ash2(w.x), w23 = ash2(w.y);
                unsigned p01lo = __builtin_amdgcn_perm(v1.x, v0.x, 0x05040100);
                unsigned p01hi = __builtin_amdgcn_perm(v1.x, v0.x, 0x07060302);
                unsigned p23lo = __builtin_amdgcn_perm(v3.x, v2.x, 0x05040100);
                unsigned p23hi = __builtin_amdgcn_perm(v3.x, v2.x, 0x07060302);
                a0 = __builtin_amdgcn_fdot2(w01, ash2(p01lo), a0, false);
                a0 = __builtin_amdgcn_fdot2(w23, ash2(p23lo), a0, false);
                a1 = __builtin_amdgcn_fdot2(w01, ash2(p01hi), a1, false);
                a1 = __builtin_amdgcn_fdot2(w23, ash2(p23hi), a1, false);
                unsigned q01lo = __builtin_amdgcn_perm(v1.y, v0.y, 0x05040100);
                unsigned q01hi = __builtin_amdgcn_perm(v1.y, v0.y, 0x07060302);
                unsigned q23lo = __builtin_amdgcn_perm(v3.y, v2.y, 0x05040100);
                unsigned q23hi = __builtin_amdgcn_perm(v3.y, v2.y, 0x07060302);
                a2 = __builtin_amdgcn_fdot2(w01, ash2(q01lo), a2, false);
                a2 = __builtin_amdgcn_fdot2(w23, ash2(q23lo), a2, false);
                a3 = __builtin_amdgcn_fdot2(w01, ash2(q01hi), a3, false);
                a3 = __builtin_amdgcn_fdot2(w23, ash2(q23hi), a3, false);
            }
            // consume globals
            #pragma unroll
            for (int pi = 0; pi < 4; pi++) {
                half2_t w01 = ash2(gw[pi].x), w23 = ash2(gw[pi].y);
                unsigned p01lo = __builtin_amdgcn_perm(gv1[pi].x, gv0[pi].x, 0x05040100);
                unsigned p01hi = __builtin_amdgcn_perm(gv1[pi].x, gv0[pi].x, 0x07060302);
                unsigned p23lo = __builtin_amdgcn_perm(gv3[pi].x, gv2[pi].x, 0x05040100);
                unsigned p23hi = __builtin_amdgcn_perm(gv3[pi].x, gv2[pi].x, 0x07060302);
                a0 = __builtin_amdgcn_fdot2(w01, ash2(p01lo), a0, false);
                a0 = __builtin_amdgcn_fdot2(w23, ash2(p23lo), a0, false);
                a1 = __builtin_amdgcn_fdot2(w01, ash2(p01hi), a1, false);
                a1 = __builtin_amdgcn_fdot2(w23, ash2(p23hi), a1, false);
                unsigned q01lo = __builtin_amdgcn_perm(gv1[pi].y, gv0[pi].y, 0x05040100);
                unsigned q01hi = __builtin_amdgcn_perm(gv1[pi].y, gv0[pi].y, 0x07060302);
                unsigned q23lo = __builtin_amdgcn_perm(gv3[pi].y, gv2[pi].y, 0x05040100);
                unsigned q23hi = __builtin_amdgcn_perm(gv3[pi].y, gv2[pi].y, 0x07060302);
                a2 = __builtin_amdgcn_fdot2(w01, ash2(q01lo), a2, false);
                a2 = __builtin_amdgcn_fdot2(w23, ash2(q23lo), a2, false);
                a3 = __builtin_amdgcn_fdot2(w01, ash2(q01hi), a3, false);
                a3 = __builtin_amdgcn_fdot2(w23, ash2(q23hi), a3, false);
            }
            // combine the two 8-lane halves (sub ^ 8)
            a0 += __shfl_xor(a0, 8);
            a1 += __shfl_xor(a1, 8);
            a2 += __shfl_xor(a2, 8);
            a3 += __shfl_xor(a3, 8);
            if (sub < 8 && lq < NQB) {
                const size_t bq = bq0 + lq;
                ushort4 o;
                o.x = f2bf(a0); o.y = f2bf(a1);
                o.z = f2bf(a2); o.w = f2bf(a3);
                *(ushort4*)(sampled + bq * 256 + h * 32 + dsh) = o;
            }
        }
        if (p + 1 >= NPASS) break;
        __syncthreads();   // phase2 readers done before s_w overwrite

        // ---------------- phase 1 for pass p+1 ----------------
        {
            const int ql = tid >> 4, lp = tid & 15;
            const int l  = lp >> 2;
            const int lq = min((p + 1) * 64 + ql, NQB - 1);
            const size_t bq = bq0 + lq;
            const int Wl = Hs[l];

            unsigned od = *(const unsigned*)(off + bq * 256 + h * 32 + lp * 2);
            float ox = bflo(od), oy = bfhi(od);
            float lgt = bflo((unsigned)awl[bq * 128 + h * 16 + lp]);
            float e = __expf(lgt);
            float sum = e;
            sum += __shfl_xor(sum, 1, 16);
            sum += __shfl_xor(sum, 2, 16);
            sum += __shfl_xor(sum, 4, 16);
            sum += __shfl_xor(sum, 8, 16);
            float aw = e * __builtin_amdgcn_rcpf(sum);

            float2 rp = *(const float2*)(refp + bq * 8 + l * 2);
            float x = rp.x * (float)Wl + ox - 0.5f;
            float y = rp.y * (float)Wl + oy - 0.5f;
            float x0f = floorf(x), y0f = floorf(y);
            float wx = x - x0f, wy = y - y0f;
            int x0 = (int)x0f, y0 = (int)y0f;
            bool vx0 = (x0 >= 0) & (x0 < Wl);
            bool vx1 = (x0 + 1 >= 0) & (x0 + 1 < Wl);
            bool vy0 = (y0 >= 0) & (y0 < Wl);
            bool vy1 = (y0 + 1 >= 0) & (y0 + 1 < Wl);
            int cx0 = min(max(x0, 0), Wl - 1);
            int cx1 = min(max(x0 + 1, 0), Wl - 1);
            int cy0 = min(max(y0, 0), Wl - 1);
            int cy1 = min(max(y0 + 1, 0), Wl - 1);
            float w00 = (vx0 && vy0) ? (1.f - wx) * (1.f - wy) * aw : 0.f;
            float w01 = (vx1 && vy0) ? wx * (1.f - wy) * aw : 0.f;
            float w10 = (vx0 && vy1) ? (1.f - wx) * wy * aw : 0.f;
            float w11 = (vx1 && vy1) ? wx * wy * aw : 0.f;
            const int rec = ql * 17 + lp;
            const int bs = base2[l];
            s_w[rec] = make_uint2(pk2u(__builtin_amdgcn_cvt_pkrtz(w00, w01)),
                                  pk2u(__builtin_amdgcn_cvt_pkrtz(w10, w11)));
            s_iv[rec] = make_ushort4((ushort_t)(bs + cy0 * Wl + cx0),
                                     (ushort_t)(bs + cy0 * Wl + cx1),
                                     (ushort_t)(bs + cy1 * Wl + cx0),
                                     (ushort_t)(bs + cy1 * Wl + cx1));
        }
        __syncthreads();   // s_w/s_iv for pass p+1 visible
    }
}

extern "C" void kernel_launch(void* const* d_in, const int* in_sizes, int n_in,
                              void* d_out, int out_size, void* d_ws, size_t ws_size,
                              hipStream_t stream) {
    const float* query = (const float*)d_in[0];
    const float* refp  = (const float*)d_in[1];
    const float* value = (const float*)d_in[2];
    const float* Wv    = (const float*)d_in[4];
    const float* bv    = (const float*)d_in[5];
    const float* Woff  = (const float*)d_in[6];
    const float* boff  = (const float*)d_in[7];
    const float* Wattn = (const float*)d_in[8];
    const float* battn = (const float*)d_in[9];
    const float* Wo    = (const float*)d_in[10];
    const float* bo    = (const float*)d_in[11];
    float* out = (float*)d_out;

    ushort_t* ws = (ushort_t*)d_ws;
    ushort_t* off_b   = ws;                       // 33600*256
    ushort_t* awl_b   = off_b + 8601600;          // 33600*128
    ushort_t* value_b = awl_b + 4300800;          // 34000*256
    ushort_t* query_b = value_b + 8704000;        // 33600*256 (aliased w/ sampled)
    ushort_t* vperm_b = query_b + 8601600;        // 34000*256 (f16)
    ushort_t* BT      = vperm_b + 8704000;        // 896*256
    ushort_t* sampled_b = query_b;                // alias: query dead after gemm_fused

    prep_all<<<dim3(17796), 256, 0, stream>>>(
        value, query, Wv, Woff, Wattn, Wo, value_b, query_b, BT);

    gemm_fused<<<dim3(532 + 789), 256, 0, stream>>>(
        value_b, query_b, BT, bv, boff, battn, vperm_b, off_b, awl_b);

    msda_sample<<<dim3(512), 1024, 0, stream>>>(
        vperm_b, off_b, awl_b, refp, sampled_b);

    gemm_out<<<dim3(526), 256, 0, stream>>>(
        sampled_b, BT + 163840, bo, out);
}